// Round 12
// baseline (381.426 us; speedup 1.0000x reference)
//
#include <hip/hip_runtime.h>
#include <math.h>

#define HH 512
#define WW 512
#define HW (HH * WW)
#define PW 514                    // padded width/height
#define PPIX (PW * PW)

#define B_U 20992                 // ushorts per B buffer (41 loads x 512)
#define LDS_BYTES (2 * B_U * 2)   // 83968 B (B double-buffer only; A lives in VGPRs)

typedef short bf16x8 __attribute__((ext_vector_type(8)));
typedef float f32x4 __attribute__((ext_vector_type(4)));

__device__ __forceinline__ ushort f2bf(float f) {
    union { float f; uint u; } c; c.f = f;
    uint u = c.u;
    return (ushort)((u + 0x7fffu + ((u >> 16) & 1u)) >> 16);
}

__device__ __forceinline__ uint cvtpk(float a, float b) {
    uint r;
    asm("v_cvt_pk_bf16_f32 %0, %1, %2" : "=v"(r) : "v"(a), "v"(b));
    return r;
}

// ---------------- kernel 1: styles ----------------
__global__ void k_styles(const float* __restrict__ wsv, const float* __restrict__ aw,
                         const float* __restrict__ ab, float* __restrict__ styles) {
    int bid = blockIdx.x;
    int b = bid >> 6, ci = bid & 63;
    int l = threadIdx.x;
    const float* wrow = wsv + b * 512;
    const float* arow = aw + ci * 512;
    float s = 0.f;
    #pragma unroll
    for (int j = 0; j < 8; ++j)
        s += wrow[l + 64 * j] * arow[l + 64 * j];
    #pragma unroll
    for (int off = 32; off; off >>= 1)
        s += __shfl_xor(s, off, 64);
    if (l == 0)
        styles[b * 64 + ci] = s * 0.044194173824159216f + ab[ci];
}

// ------------- kernel 2: modulate+demodulate -> bf16 [b][co][off 9][ci 64] (plain) -------------
__global__ void k_wmod(const float* __restrict__ cw, const float* __restrict__ styles,
                       ushort* __restrict__ wb) {
    int b = blockIdx.x >> 6, co = blockIdx.x & 63;
    int ci = threadIdx.x;
    float st = styles[b * 64 + ci];
    const float* wp = cw + (co * 64 + ci) * 9;
    float wv[9];
    float ss = 0.f;
    #pragma unroll
    for (int k = 0; k < 9; ++k) { wv[k] = wp[k] * st; ss += wv[k] * wv[k]; }
    #pragma unroll
    for (int off = 32; off; off >>= 1)
        ss += __shfl_xor(ss, off, 64);
    float dm = 1.0f / sqrtf(ss + 1e-8f);
    #pragma unroll
    for (int k = 0; k < 9; ++k)
        wb[((size_t)(b * 64 + co) * 9 + k) * 64 + ci] = f2bf(wv[k] * dm);
}

// ------------- kernel 2c: x fp32 NCHW -> xp bf16 [b][gy+1][gx+1][ci], pad fused -------------
__global__ __launch_bounds__(256) void k_xpose(
    const float* __restrict__ x, ushort* __restrict__ xp) {
    const int t = threadIdx.x;
    const int bid = blockIdx.x;

    if (bid >= 8192) {            // ---- fused zeropad of the border ----
        int id = (bid - 8192) * 256 + t;
        if (id >= 4 * 2052) return;
        int b = id / 2052, r = id % 2052;
        int gyp, gxp;
        if (r < 514)       { gyp = 0;        gxp = r; }
        else if (r < 1028) { gyp = 513;      gxp = r - 514; }
        else if (r < 1540) { gyp = r - 1027; gxp = 0; }
        else               { gyp = r - 1539; gxp = 513; }
        ushort* p = xp + (((size_t)b * PW + gyp) * PW + gxp) * 64;
        uint4 z = make_uint4(0, 0, 0, 0);
        #pragma unroll
        for (int i = 0; i < 8; ++i) *(uint4*)(p + i * 8) = z;
        return;
    }

    __shared__ ushort lt[128 * 68];
    const int gxt = bid & 3;
    const int gy  = (bid >> 2) & 511;
    const int b   = bid >> 11;

    const float* xb = x + (size_t)b * 64 * HW + (size_t)gy * WW + gxt * 128;
    const int ci0 = 8 * (t >> 5);
    const int gxc = t & 31;

    f32x4 v[8];
    #pragma unroll
    for (int j = 0; j < 8; ++j)
        v[j] = *(const f32x4*)(xb + (size_t)(ci0 + j) * HW + gxc * 4);

    #pragma unroll
    for (int p = 0; p < 4; ++p) {
        int px = gxc * 4 + p;
        int rowp = ((px & 3) * 32 + (px >> 2)) * 68;
        #pragma unroll
        for (int cg = 0; cg < 2; ++cg) {
            uint lo = cvtpk(v[4 * cg + 0][p], v[4 * cg + 1][p]);
            uint hi = cvtpk(v[4 * cg + 2][p], v[4 * cg + 3][p]);
            *(uint2*)&lt[rowp + ci0 + 4 * cg] = make_uint2(lo, hi);
        }
    }
    __syncthreads();

    const int px = t >> 1, half = t & 1;
    const int rowp = ((px & 3) * 32 + (px >> 2)) * 68 + half * 32;
    uint4 o0 = *(uint4*)&lt[rowp + 0];
    uint4 o1 = *(uint4*)&lt[rowp + 8];
    uint4 o2 = *(uint4*)&lt[rowp + 16];
    uint4 o3 = *(uint4*)&lt[rowp + 24];
    ushort* dst = xp + (((size_t)b * PW + (gy + 1)) * PW + (gxt * 128 + px + 1)) * 64
                     + half * 32;
    *(uint4*)(dst + 0)  = o0;
    *(uint4*)(dst + 8)  = o1;
    *(uint4*)(dst + 16) = o2;
    *(uint4*)(dst + 24) = o3;
}

// ------------- kernel 3: persistent 8-wave MFMA conv, A-in-REGISTERS, B double-buffered -------------
// 256 blocks (1/CU), 512 threads (8 waves = 2/SIMD). Block = (b, 16-row band, 256-col half).
// Per wave: r_m=2 (co-half via wm), r_n=4 (rows wn*4..+3). A-frags (36 x bf16x8 = 144 VGPR)
// loaded once from global; LDS holds only B ([18 rows][18 cols][64 ci] x 2 buffers).
// Inner phase: 4 ds_read_b128 -> 8 MFMA (ratio 0.5 = half of R10's LDS traffic).
// __launch_bounds__(512, 2): 2 waves/SIMD -> 256-VGPR budget so areg does NOT spill
// (R11's 128-VGPR default spilled areg to scratch: +116MB HBM traffic).
__global__ __launch_bounds__(512, 2) void k_conv(
    const ushort* __restrict__ xp,    // [4][514][514][64] bf16 padded
    const ushort* __restrict__ wb,    // [4][64co][9][64ci] bf16 (plain)
    const float* __restrict__ noise,  // [4][1][512][512]
    const float* __restrict__ bias,   // [64]
    float* __restrict__ out) {        // [4][64][512][512] fp32
    extern __shared__ __align__(16) ushort lds[];

    const int t = threadIdx.x;
    const int w = t >> 6;
    const int lane = t & 63;
    const int lr = lane & 15;
    const int lq = lane >> 4;
    const int wm = w >> 2;               // 0..1 -> co half
    const int wn = w & 3;                // 0..3 -> row quarter

    const int blk = blockIdx.x;
    const int b = blk >> 6;
    const int band = (blk >> 1) & 31;
    const int ch = blk & 1;
    const int ty = band * 16;
    const int tx0 = ch * 256;

    const ushort* xpb = xp + (size_t)b * PPIX * 64;

    // ---- A into registers: 36 bf16x8 (fully static indexing) ----
    const ushort* wA = wb + (size_t)b * 64 * 576;
    bf16x8 areg[2][9][2];
    #pragma unroll
    for (int m = 0; m < 2; ++m) {
        const ushort* pco = wA + (wm * 32 + m * 16 + lr) * 576 + lq * 8;
        #pragma unroll
        for (int off = 0; off < 9; ++off)
            #pragma unroll
            for (int kb = 0; kb < 2; ++kb)
                areg[m][off][kb] = *(const bf16x8*)(pco + off * 64 + kb * 32);
    }

    // ---- per-j staging source offsets (tile-invariant; div-by-18 hoisted) ----
    int soff[6];
    #pragma unroll
    for (int jj = 0; jj < 6; ++jj) {
        int j = w + jj * 8;
        if (j < 41) {
            int c = j * 64 + lane;
            int c2 = c < 2591 ? c : 2591;      // tail clamp (src only; dst stays linear)
            int cig = c2 & 7;
            int pxl = c2 >> 3;
            int row = pxl / 18;
            int lcol = pxl - row * 18;
            int gsrc = cig ^ (lcol & 7);       // pre-swizzled source ci-group (R8-proven)
            soff[jj] = ((ty + row) * PW + lcol) * 64 + gsrc * 8;
        } else soff[jj] = 0;
    }

    // B read offsets (dy=0, kb=0): row = wn*4+i, [row][lcol][ci-swizzled] (R8-proven)
    int bidx[4][3];
    #pragma unroll
    for (int i = 0; i < 4; ++i)
        #pragma unroll
        for (int dx = 0; dx < 3; ++dx) {
            int lcol = lr + dx;
            bidx[i][dx] = ((wn * 4 + i) * 18 + lcol) * 64 + ((lq * 8) ^ ((lcol & 7) << 3));
        }

    f32x4 bv[2];
    #pragma unroll
    for (int m = 0; m < 2; ++m)
        bv[m] = *(const f32x4*)&bias[wm * 32 + m * 16 + lq * 4];
    const float* nz = noise + (size_t)b * HW;

    // ---- prologue: stage tile0 into buf0 ----
    #pragma unroll
    for (int jj = 0; jj < 6; ++jj) {
        int j = w + jj * 8;
        if (j < 41)
            __builtin_amdgcn_global_load_lds(
                (const __attribute__((address_space(1))) unsigned int*)(xpb + soff[jj] + tx0 * 64),
                (__attribute__((address_space(3))) unsigned int*)&lds[j * 512],
                16, 0, 0);
    }
    asm volatile("s_waitcnt vmcnt(0)" ::: "memory");
    __syncthreads();

    int p = 0;
    for (int it = 0; it < 16; ++it) {
        const int tx = tx0 + it * 16;
        const int gx = tx + lr;

        // issue next tile's staging (hidden under compute)
        if (it < 15) {
            #pragma unroll
            for (int jj = 0; jj < 6; ++jj) {
                int j = w + jj * 8;
                if (j < 41)
                    __builtin_amdgcn_global_load_lds(
                        (const __attribute__((address_space(1))) unsigned int*)
                            (xpb + soff[jj] + (tx + 16) * 64),
                        (__attribute__((address_space(3))) unsigned int*)
                            &lds[(p ^ 1) * B_U + j * 512],
                        16, 0, 0);
            }
        }

        // noise loads (drained by the vmcnt(0) before epilogue)
        float nv[4];
        int gyv[4];
        #pragma unroll
        for (int i = 0; i < 4; ++i) {
            gyv[i] = ty + wn * 4 + i;
            nv[i] = nz[gyv[i] * WW + gx];
        }

        // ---- compute from buf p: 4 ds_read -> 8 MFMA per phase ----
        const ushort* bufp = &lds[p * B_U];
        f32x4 acc[2][4];
        #pragma unroll
        for (int m = 0; m < 2; ++m)
            #pragma unroll
            for (int i = 0; i < 4; ++i) acc[m][i] = (f32x4){0.f, 0.f, 0.f, 0.f};

        #pragma unroll
        for (int dy = 0; dy < 3; ++dy) {
            #pragma unroll
            for (int dx = 0; dx < 3; ++dx) {
                #pragma unroll
                for (int kb = 0; kb < 2; ++kb) {
                    const int off = dy * 3 + dx;
                    bf16x8 bfr[4];
                    #pragma unroll
                    for (int i = 0; i < 4; ++i)
                        bfr[i] = *(const bf16x8*)
                            &bufp[(bidx[i][dx] + dy * (18 * 64)) ^ (kb << 5)];
                    #pragma unroll
                    for (int m = 0; m < 2; ++m)
                        #pragma unroll
                        for (int i = 0; i < 4; ++i)
                            acc[m][i] = __builtin_amdgcn_mfma_f32_16x16x32_bf16(
                                areg[m][off][kb], bfr[i], acc[m][i], 0, 0, 0);
                }
            }
        }

        // next-tile stages + noise had the whole compute to land; drain + swap
        asm volatile("s_waitcnt vmcnt(0)" ::: "memory");
        __syncthreads();

        // ---- epilogue: +noise, +bias, lrelu*sqrt2, clamp, store ----
        #pragma unroll
        for (int m = 0; m < 2; ++m) {
            #pragma unroll
            for (int i = 0; i < 4; ++i) {
                #pragma unroll
                for (int rg = 0; rg < 4; ++rg) {
                    int co = wm * 32 + m * 16 + lq * 4 + rg;
                    float y = acc[m][i][rg] + nv[i] + bv[m][rg];
                    y = (y >= 0.f ? y : 0.2f * y) * 1.41421356237f;
                    y = fminf(fmaxf(y, -256.f), 256.f);
                    out[((size_t)(b * 64 + co) * HH + gyv[i]) * WW + gx] = y;
                }
            }
        }
        p ^= 1;
    }
}

extern "C" void kernel_launch(void* const* d_in, const int* in_sizes, int n_in,
                              void* d_out, int out_size, void* d_ws, size_t ws_size,
                              hipStream_t stream) {
    const float* x     = (const float*)d_in[0];
    const float* wsv   = (const float*)d_in[1];
    const float* noise = (const float*)d_in[2];
    const float* aw    = (const float*)d_in[3];
    const float* ab    = (const float*)d_in[4];
    const float* cw    = (const float*)d_in[5];
    const float* bias  = (const float*)d_in[6];
    float* out = (float*)d_out;

    float*  styles = (float*)d_ws;                          // 1 KB
    ushort* wb16   = (ushort*)((char*)d_ws + 1024);         // 294912 B
    ushort* xpad   = (ushort*)((char*)d_ws + (1 << 20));    // 135.3 MB

    hipFuncSetAttribute((const void*)k_conv,
                        hipFuncAttributeMaxDynamicSharedMemorySize, LDS_BYTES);

    k_styles<<<256, 64, 0, stream>>>(wsv, aw, ab, styles);
    k_wmod<<<256, 64, 0, stream>>>(cw, styles, wb16);
    k_xpose<<<8225, 256, 0, stream>>>(x, xpad);
    k_conv<<<256, 512, LDS_BYTES, stream>>>(xpad, wb16, noise, bias, out);
}

// Round 13
// 260.472 us; speedup vs baseline: 1.4644x; 1.4644x over previous
//
#include <hip/hip_runtime.h>
#include <math.h>

#define HH 512
#define WW 512
#define HW (HH * WW)
#define PW 514                    // padded width/height
#define PPIX (PW * PW)

#define A_U 36864                 // 64co*9off*64ci ushorts = 73728 B
#define B_U 22016                 // 43 loads x 512 ushorts = 44032 B per B buffer
#define LDS_BYTES ((A_U + 2 * B_U) * 2)   // 161792 B <= 160 KiB pool

typedef short bf16x8 __attribute__((ext_vector_type(8)));
typedef float f32x4  __attribute__((ext_vector_type(4)));
typedef float f32x16 __attribute__((ext_vector_type(16)));

__device__ __forceinline__ ushort f2bf(float f) {
    union { float f; uint u; } c; c.f = f;
    uint u = c.u;
    return (ushort)((u + 0x7fffu + ((u >> 16) & 1u)) >> 16);
}

__device__ __forceinline__ uint cvtpk(float a, float b) {
    uint r;
    asm("v_cvt_pk_bf16_f32 %0, %1, %2" : "=v"(r) : "v"(a), "v"(b));
    return r;
}

// ---------------- kernel 1: styles ----------------
__global__ void k_styles(const float* __restrict__ wsv, const float* __restrict__ aw,
                         const float* __restrict__ ab, float* __restrict__ styles) {
    int bid = blockIdx.x;
    int b = bid >> 6, ci = bid & 63;
    int l = threadIdx.x;
    const float* wrow = wsv + b * 512;
    const float* arow = aw + ci * 512;
    float s = 0.f;
    #pragma unroll
    for (int j = 0; j < 8; ++j)
        s += wrow[l + 64 * j] * arow[l + 64 * j];
    #pragma unroll
    for (int off = 32; off; off >>= 1)
        s += __shfl_xor(s, off, 64);
    if (l == 0)
        styles[b * 64 + ci] = s * 0.044194173824159216f + ab[ci];
}

// ------------- kernel 2: modulate+demodulate -> bf16 [b][co][off 9][ci 64] -------------
// ci-group (ci>>3) stored XORed with (co&7): conflict-free A ds_reads after a
// purely LINEAR global_load_lds stage (swizzle baked at write time). (R8/R10-proven)
__global__ void k_wmod(const float* __restrict__ cw, const float* __restrict__ styles,
                       ushort* __restrict__ wb) {
    int b = blockIdx.x >> 6, co = blockIdx.x & 63;
    int ci = threadIdx.x;
    float st = styles[b * 64 + ci];
    const float* wp = cw + (co * 64 + ci) * 9;
    float wv[9];
    float ss = 0.f;
    #pragma unroll
    for (int k = 0; k < 9; ++k) { wv[k] = wp[k] * st; ss += wv[k] * wv[k]; }
    #pragma unroll
    for (int off = 32; off; off >>= 1)
        ss += __shfl_xor(ss, off, 64);
    float dm = 1.0f / sqrtf(ss + 1e-8f);
    int cisw = ((((ci >> 3) ^ co) & 7) << 3) | (ci & 7);
    #pragma unroll
    for (int k = 0; k < 9; ++k)
        wb[((size_t)(b * 64 + co) * 9 + k) * 64 + cisw] = f2bf(wv[k] * dm);
}

// ------------- kernel 2c: x fp32 NCHW -> xp bf16 [b][gy+1][gx+1][ci], pad fused -------------
__global__ __launch_bounds__(256) void k_xpose(
    const float* __restrict__ x, ushort* __restrict__ xp) {
    const int t = threadIdx.x;
    const int bid = blockIdx.x;

    if (bid >= 8192) {            // ---- fused zeropad of the border ----
        int id = (bid - 8192) * 256 + t;
        if (id >= 4 * 2052) return;
        int b = id / 2052, r = id % 2052;
        int gyp, gxp;
        if (r < 514)       { gyp = 0;        gxp = r; }
        else if (r < 1028) { gyp = 513;      gxp = r - 514; }
        else if (r < 1540) { gyp = r - 1027; gxp = 0; }
        else               { gyp = r - 1539; gxp = 513; }
        ushort* p = xp + (((size_t)b * PW + gyp) * PW + gxp) * 64;
        uint4 z = make_uint4(0, 0, 0, 0);
        #pragma unroll
        for (int i = 0; i < 8; ++i) *(uint4*)(p + i * 8) = z;
        return;
    }

    __shared__ ushort lt[128 * 68];
    const int gxt = bid & 3;
    const int gy  = (bid >> 2) & 511;
    const int b   = bid >> 11;

    const float* xb = x + (size_t)b * 64 * HW + (size_t)gy * WW + gxt * 128;
    const int ci0 = 8 * (t >> 5);
    const int gxc = t & 31;

    f32x4 v[8];
    #pragma unroll
    for (int j = 0; j < 8; ++j)
        v[j] = *(const f32x4*)(xb + (size_t)(ci0 + j) * HW + gxc * 4);

    #pragma unroll
    for (int p = 0; p < 4; ++p) {
        int px = gxc * 4 + p;
        int rowp = ((px & 3) * 32 + (px >> 2)) * 68;
        #pragma unroll
        for (int cg = 0; cg < 2; ++cg) {
            uint lo = cvtpk(v[4 * cg + 0][p], v[4 * cg + 1][p]);
            uint hi = cvtpk(v[4 * cg + 2][p], v[4 * cg + 3][p]);
            *(uint2*)&lt[rowp + ci0 + 4 * cg] = make_uint2(lo, hi);
        }
    }
    __syncthreads();

    const int px = t >> 1, half = t & 1;
    const int rowp = ((px & 3) * 32 + (px >> 2)) * 68 + half * 32;
    uint4 o0 = *(uint4*)&lt[rowp + 0];
    uint4 o1 = *(uint4*)&lt[rowp + 8];
    uint4 o2 = *(uint4*)&lt[rowp + 16];
    uint4 o3 = *(uint4*)&lt[rowp + 24];
    ushort* dst = xp + (((size_t)b * PW + (gy + 1)) * PW + (gxt * 128 + px + 1)) * 64
                     + half * 32;
    *(uint4*)(dst + 0)  = o0;
    *(uint4*)(dst + 8)  = o1;
    *(uint4*)(dst + 16) = o2;
    *(uint4*)(dst + 24) = o3;
}

// ------------- kernel 3: persistent 4-wave MFMA conv, 32x32x16, A-in-LDS, B dbuf -------------
// 256 blocks (1/CU), 256 threads (4 waves). Block = (b, 8-row band); 16 col-tiles
// of 8 rows x 32 cols, pipelined: issue gload_lds(B next) -> compute cur ->
// vmcnt(0)+barrier -> store cur.
// Per wave: row-pair w; r_m=2 (co 0-31 / 32-63) x r_n=2 (col halves) at 32x32x16
// -> per (tap,kb16): 4 ds_read_b128 -> 4 MFMA of 32k FLOP (half of R10's LDS traffic).
__global__ __launch_bounds__(256, 1) void k_conv(
    const ushort* __restrict__ xp,    // [4][514][514][64] bf16 padded
    const ushort* __restrict__ wb,    // [4][64co][9][64ci] bf16 (swizzle baked)
    const float* __restrict__ noise,  // [4][1][512][512]
    const float* __restrict__ bias,   // [64]
    float* __restrict__ out) {        // [4][64][512][512] fp32
    extern __shared__ __align__(16) ushort lds[];

    const int t = threadIdx.x;
    const int w = t >> 6;                // wave 0..3 = row-pair
    const int lane = t & 63;
    const int n5 = lane & 31;            // MFMA N/M lane coord
    const int hl = lane >> 5;            // k-half (8 ci)
    const int blk = blockIdx.x;
    const int b = blk >> 6;
    const int band = blk & 63;
    const int ty = band * 8;

    const ushort* xpb = xp + (size_t)b * PPIX * 64;
    const ushort* wA  = wb + (size_t)b * 64 * 576;

    // ---- stage A once: 72 x 1KB linear copy ----
    #pragma unroll
    for (int jj = 0; jj < 18; ++jj) {
        int j = w + jj * 4;
        const ushort* src = wA + j * 512 + lane * 8;
        __builtin_amdgcn_global_load_lds(
            (const __attribute__((address_space(1))) unsigned int*)src,
            (__attribute__((address_space(3))) unsigned int*)&lds[j * 512],
            16, 0, 0);
    }

    // ---- B staging source offsets (tile-invariant) ----
    int soff[11];
    #pragma unroll
    for (int jj = 0; jj < 11; ++jj) {
        int j = w + jj * 4;
        if (j < 43) {
            int c = j * 64 + lane;
            int c2 = c < 2719 ? c : 2719;  // tail clamp (src only; dst stays linear)
            int cig = c2 & 7;
            int pxl = c2 >> 3;
            int row = pxl / 34;
            int lcol = pxl - row * 34;
            int gsrc = cig ^ (lcol & 7);   // pre-swizzled source ci-group (R8-proven)
            soff[jj] = ((ty + row) * PW + lcol) * 64 + gsrc * 8;
        } else soff[jj] = 0;
    }

    // ---- prologue: stage tile0 (tx=0) into buf0 ----
    #pragma unroll
    for (int jj = 0; jj < 11; ++jj) {
        int j = w + jj * 4;
        if (j < 43)
            __builtin_amdgcn_global_load_lds(
                (const __attribute__((address_space(1))) unsigned int*)(xpb + soff[jj]),
                (__attribute__((address_space(3))) unsigned int*)&lds[A_U + j * 512],
                16, 0, 0);
    }
    asm volatile("s_waitcnt vmcnt(0)" ::: "memory");
    __syncthreads();

    // ---- A read bases (slot = (2kb ^ hl ^ (co&7)); kb applied as idx ^ (kb<<4)) ----
    int aidx[2];
    #pragma unroll
    for (int mt = 0; mt < 2; ++mt)
        aidx[mt] = (mt * 32 + n5) * 576 + ((hl ^ (n5 & 7)) << 3);

    // ---- B read bases: row = 2w + (n5>>4), col = i*16 + (n5&15) + dx ----
    int bidx[2][3];
    const int brow = 2 * w + (n5 >> 4);
    #pragma unroll
    for (int i = 0; i < 2; ++i)
        #pragma unroll
        for (int dx = 0; dx < 3; ++dx) {
            int lcol = i * 16 + (n5 & 15) + dx;
            bidx[i][dx] = (brow * 34 + lcol) * 64 + ((hl ^ (lcol & 7)) << 3);
        }

    const float* nz = noise + (size_t)b * HW;
    const int orow = ty + brow;           // output row for this lane

    int p = 0;
    for (int it = 0; it < 16; ++it) {
        const int tx = it * 32;

        // issue next tile's staging (hidden under compute)
        if (it < 15) {
            #pragma unroll
            for (int jj = 0; jj < 11; ++jj) {
                int j = w + jj * 4;
                if (j < 43)
                    __builtin_amdgcn_global_load_lds(
                        (const __attribute__((address_space(1))) unsigned int*)
                            (xpb + soff[jj] + (tx + 32) * 64),
                        (__attribute__((address_space(3))) unsigned int*)
                            &lds[A_U + (p ^ 1) * B_U + j * 512],
                        16, 0, 0);
            }
        }

        // noise loads (drained by vmcnt(0) before epilogue)
        float nv[2];
        #pragma unroll
        for (int i = 0; i < 2; ++i)
            nv[i] = nz[orow * WW + tx + i * 16 + (n5 & 15)];

        // ---- compute from buf p: 4 ds_read_b128 -> 4 MFMA(32x32x16) per phase ----
        const ushort* bufp = &lds[A_U + p * B_U];
        f32x16 acc[2][2];
        #pragma unroll
        for (int mt = 0; mt < 2; ++mt)
            #pragma unroll
            for (int i = 0; i < 2; ++i)
                acc[mt][i] = (f32x16){0.f,0.f,0.f,0.f,0.f,0.f,0.f,0.f,
                                      0.f,0.f,0.f,0.f,0.f,0.f,0.f,0.f};

        #pragma unroll
        for (int dy = 0; dy < 3; ++dy) {
            #pragma unroll
            for (int dx = 0; dx < 3; ++dx) {
                const int off = dy * 3 + dx;
                #pragma unroll
                for (int kb = 0; kb < 4; ++kb) {
                    bf16x8 afr[2], bfr[2];
                    #pragma unroll
                    for (int mt = 0; mt < 2; ++mt)
                        afr[mt] = *(const bf16x8*)
                            &lds[(aidx[mt] + off * 64) ^ (kb << 4)];
                    #pragma unroll
                    for (int i = 0; i < 2; ++i)
                        bfr[i] = *(const bf16x8*)
                            &bufp[(bidx[i][dx] + dy * (34 * 64)) ^ (kb << 4)];
                    #pragma unroll
                    for (int mt = 0; mt < 2; ++mt)
                        #pragma unroll
                        for (int i = 0; i < 2; ++i)
                            acc[mt][i] = __builtin_amdgcn_mfma_f32_32x32x16_bf16(
                                afr[mt], bfr[i], acc[mt][i], 0, 0, 0);
                }
            }
        }

        // next-tile stages + noise had the whole compute to land; drain + swap
        asm volatile("s_waitcnt vmcnt(0)" ::: "memory");
        __syncthreads();

        // ---- epilogue: +noise, +bias, lrelu*sqrt2, clamp, store ----
        // C layout (m74/m101): col = lane&31 (px), row = (reg&3)+8*(reg>>2)+4*hl (co)
        #pragma unroll
        for (int mt = 0; mt < 2; ++mt) {
            #pragma unroll
            for (int i = 0; i < 2; ++i) {
                const int ocol = tx + i * 16 + (n5 & 15);
                #pragma unroll
                for (int reg = 0; reg < 16; ++reg) {
                    int co = mt * 32 + (reg & 3) + 8 * (reg >> 2) + 4 * hl;
                    float y = acc[mt][i][reg] + nv[i] + bias[co];
                    y = (y >= 0.f ? y : 0.2f * y) * 1.41421356237f;
                    y = fminf(fmaxf(y, -256.f), 256.f);
                    out[((size_t)(b * 64 + co) * HH + orow) * WW + ocol] = y;
                }
            }
        }
        p ^= 1;
    }
}

extern "C" void kernel_launch(void* const* d_in, const int* in_sizes, int n_in,
                              void* d_out, int out_size, void* d_ws, size_t ws_size,
                              hipStream_t stream) {
    const float* x     = (const float*)d_in[0];
    const float* wsv   = (const float*)d_in[1];
    const float* noise = (const float*)d_in[2];
    const float* aw    = (const float*)d_in[3];
    const float* ab    = (const float*)d_in[4];
    const float* cw    = (const float*)d_in[5];
    const float* bias  = (const float*)d_in[6];
    float* out = (float*)d_out;

    float*  styles = (float*)d_ws;                          // 1 KB
    ushort* wb16   = (ushort*)((char*)d_ws + 1024);         // 294912 B
    ushort* xpad   = (ushort*)((char*)d_ws + (1 << 20));    // 135.3 MB

    hipFuncSetAttribute((const void*)k_conv,
                        hipFuncAttributeMaxDynamicSharedMemorySize, LDS_BYTES);

    k_styles<<<256, 64, 0, stream>>>(wsv, aw, ab, styles);
    k_wmod<<<256, 64, 0, stream>>>(cw, styles, wb16);
    k_xpose<<<8225, 256, 0, stream>>>(x, xpad);
    k_conv<<<256, 256, LDS_BYTES, stream>>>(xpad, wb16, noise, bias, out);
}

// Round 14
// 236.314 us; speedup vs baseline: 1.6141x; 1.1022x over previous
//
#include <hip/hip_runtime.h>
#include <math.h>

#define HH 512
#define WW 512
#define HW (HH * WW)
#define PW 514                    // padded width/height
#define PPIX (PW * PW)

#define A_U 36864                 // 64co*9off*64ci ushorts = 73728 B
#define B_U 22016                 // 43 loads x 512 ushorts = 44032 B per B buffer
#define LDS_BYTES ((A_U + 2 * B_U) * 2)   // 161792 B <= 160 KiB pool

typedef short bf16x8 __attribute__((ext_vector_type(8)));
typedef float f32x4  __attribute__((ext_vector_type(4)));
typedef float f32x16 __attribute__((ext_vector_type(16)));

__device__ __forceinline__ ushort f2bf(float f) {
    union { float f; uint u; } c; c.f = f;
    uint u = c.u;
    return (ushort)((u + 0x7fffu + ((u >> 16) & 1u)) >> 16);
}

__device__ __forceinline__ uint cvtpk(float a, float b) {
    uint r;
    asm("v_cvt_pk_bf16_f32 %0, %1, %2" : "=v"(r) : "v"(a), "v"(b));
    return r;
}

// ---------------- kernel 1: styles ----------------
__global__ void k_styles(const float* __restrict__ wsv, const float* __restrict__ aw,
                         const float* __restrict__ ab, float* __restrict__ styles) {
    int bid = blockIdx.x;
    int b = bid >> 6, ci = bid & 63;
    int l = threadIdx.x;
    const float* wrow = wsv + b * 512;
    const float* arow = aw + ci * 512;
    float s = 0.f;
    #pragma unroll
    for (int j = 0; j < 8; ++j)
        s += wrow[l + 64 * j] * arow[l + 64 * j];
    #pragma unroll
    for (int off = 32; off; off >>= 1)
        s += __shfl_xor(s, off, 64);
    if (l == 0)
        styles[b * 64 + ci] = s * 0.044194173824159216f + ab[ci];
}

// ------------- kernel 2: modulate+demodulate -> bf16 [b][co][off 9][ci 64] -------------
// ci-group (ci>>3) stored XORed with (co&7): conflict-free A ds_reads after a
// purely LINEAR global_load_lds stage (swizzle baked at write time). (R8/R10-proven)
__global__ void k_wmod(const float* __restrict__ cw, const float* __restrict__ styles,
                       ushort* __restrict__ wb) {
    int b = blockIdx.x >> 6, co = blockIdx.x & 63;
    int ci = threadIdx.x;
    float st = styles[b * 64 + ci];
    const float* wp = cw + (co * 64 + ci) * 9;
    float wv[9];
    float ss = 0.f;
    #pragma unroll
    for (int k = 0; k < 9; ++k) { wv[k] = wp[k] * st; ss += wv[k] * wv[k]; }
    #pragma unroll
    for (int off = 32; off; off >>= 1)
        ss += __shfl_xor(ss, off, 64);
    float dm = 1.0f / sqrtf(ss + 1e-8f);
    int cisw = ((((ci >> 3) ^ co) & 7) << 3) | (ci & 7);
    #pragma unroll
    for (int k = 0; k < 9; ++k)
        wb[((size_t)(b * 64 + co) * 9 + k) * 64 + cisw] = f2bf(wv[k] * dm);
}

// ------------- kernel 2c: x fp32 NCHW -> xp bf16 [b][gy+1][gx+1][ci], pad fused -------------
__global__ __launch_bounds__(256) void k_xpose(
    const float* __restrict__ x, ushort* __restrict__ xp) {
    const int t = threadIdx.x;
    const int bid = blockIdx.x;

    if (bid >= 8192) {            // ---- fused zeropad of the border ----
        int id = (bid - 8192) * 256 + t;
        if (id >= 4 * 2052) return;
        int b = id / 2052, r = id % 2052;
        int gyp, gxp;
        if (r < 514)       { gyp = 0;        gxp = r; }
        else if (r < 1028) { gyp = 513;      gxp = r - 514; }
        else if (r < 1540) { gyp = r - 1027; gxp = 0; }
        else               { gyp = r - 1539; gxp = 513; }
        ushort* p = xp + (((size_t)b * PW + gyp) * PW + gxp) * 64;
        uint4 z = make_uint4(0, 0, 0, 0);
        #pragma unroll
        for (int i = 0; i < 8; ++i) *(uint4*)(p + i * 8) = z;
        return;
    }

    __shared__ ushort lt[128 * 68];
    const int gxt = bid & 3;
    const int gy  = (bid >> 2) & 511;
    const int b   = bid >> 11;

    const float* xb = x + (size_t)b * 64 * HW + (size_t)gy * WW + gxt * 128;
    const int ci0 = 8 * (t >> 5);
    const int gxc = t & 31;

    f32x4 v[8];
    #pragma unroll
    for (int j = 0; j < 8; ++j)
        v[j] = *(const f32x4*)(xb + (size_t)(ci0 + j) * HW + gxc * 4);

    #pragma unroll
    for (int p = 0; p < 4; ++p) {
        int px = gxc * 4 + p;
        int rowp = ((px & 3) * 32 + (px >> 2)) * 68;
        #pragma unroll
        for (int cg = 0; cg < 2; ++cg) {
            uint lo = cvtpk(v[4 * cg + 0][p], v[4 * cg + 1][p]);
            uint hi = cvtpk(v[4 * cg + 2][p], v[4 * cg + 3][p]);
            *(uint2*)&lt[rowp + ci0 + 4 * cg] = make_uint2(lo, hi);
        }
    }
    __syncthreads();

    const int px = t >> 1, half = t & 1;
    const int rowp = ((px & 3) * 32 + (px >> 2)) * 68 + half * 32;
    uint4 o0 = *(uint4*)&lt[rowp + 0];
    uint4 o1 = *(uint4*)&lt[rowp + 8];
    uint4 o2 = *(uint4*)&lt[rowp + 16];
    uint4 o3 = *(uint4*)&lt[rowp + 24];
    ushort* dst = xp + (((size_t)b * PW + (gy + 1)) * PW + (gxt * 128 + px + 1)) * 64
                     + half * 32;
    *(uint4*)(dst + 0)  = o0;
    *(uint4*)(dst + 8)  = o1;
    *(uint4*)(dst + 16) = o2;
    *(uint4*)(dst + 24) = o3;
}

// ------------- kernel 3: persistent 4-wave MFMA conv, 32x32x16, A-in-LDS, B dbuf -------------
// 256 blocks (1/CU), 256 threads (4 waves). Block = (b, 8-row band); 16 col-tiles
// of 8 rows x 32 cols.
// T4 pipeline (R14): noise -> compute(cur) -> stage_issue(next) -> stores(cur)
// -> vmcnt(63) [stage retired, stores stay IN FLIGHT] -> raw s_barrier.
// In-order vmcnt: nv-use wait (vmcnt~11) lands after compute, so prev-iter
// stores drain under compute instead of serializing the loop (R8-R13 bug:
// vmcnt(0) waited for 64KB of stores every tile).
__global__ __launch_bounds__(256, 1) void k_conv(
    const ushort* __restrict__ xp,    // [4][514][514][64] bf16 padded
    const ushort* __restrict__ wb,    // [4][64co][9][64ci] bf16 (swizzle baked)
    const float* __restrict__ noise,  // [4][1][512][512]
    const float* __restrict__ bias,   // [64]
    float* __restrict__ out) {        // [4][64][512][512] fp32
    extern __shared__ __align__(16) ushort lds[];

    const int t = threadIdx.x;
    const int w = t >> 6;                // wave 0..3 = row-pair
    const int lane = t & 63;
    const int n5 = lane & 31;            // MFMA N/M lane coord
    const int hl = lane >> 5;            // k-half (8 ci)
    const int blk = blockIdx.x;
    const int b = blk >> 6;
    const int band = blk & 63;
    const int ty = band * 8;

    const ushort* xpb = xp + (size_t)b * PPIX * 64;
    const ushort* wA  = wb + (size_t)b * 64 * 576;

    // ---- stage A once: 72 x 1KB linear copy ----
    #pragma unroll
    for (int jj = 0; jj < 18; ++jj) {
        int j = w + jj * 4;
        const ushort* src = wA + j * 512 + lane * 8;
        __builtin_amdgcn_global_load_lds(
            (const __attribute__((address_space(1))) unsigned int*)src,
            (__attribute__((address_space(3))) unsigned int*)&lds[j * 512],
            16, 0, 0);
    }

    // ---- B staging source offsets (tile-invariant) ----
    int soff[11];
    #pragma unroll
    for (int jj = 0; jj < 11; ++jj) {
        int j = w + jj * 4;
        if (j < 43) {
            int c = j * 64 + lane;
            int c2 = c < 2719 ? c : 2719;  // tail clamp (src only; dst stays linear)
            int cig = c2 & 7;
            int pxl = c2 >> 3;
            int row = pxl / 34;
            int lcol = pxl - row * 34;
            int gsrc = cig ^ (lcol & 7);   // pre-swizzled source ci-group (R8-proven)
            soff[jj] = ((ty + row) * PW + lcol) * 64 + gsrc * 8;
        } else soff[jj] = 0;
    }

    // ---- prologue: stage tile0 (tx=0) into buf0 ----
    #pragma unroll
    for (int jj = 0; jj < 11; ++jj) {
        int j = w + jj * 4;
        if (j < 43)
            __builtin_amdgcn_global_load_lds(
                (const __attribute__((address_space(1))) unsigned int*)(xpb + soff[jj]),
                (__attribute__((address_space(3))) unsigned int*)&lds[A_U + j * 512],
                16, 0, 0);
    }
    asm volatile("s_waitcnt vmcnt(0)" ::: "memory");
    __syncthreads();

    // ---- A read bases ----
    int aidx[2];
    #pragma unroll
    for (int mt = 0; mt < 2; ++mt)
        aidx[mt] = (mt * 32 + n5) * 576 + ((hl ^ (n5 & 7)) << 3);

    // ---- B read bases: row = 2w + (n5>>4), col = i*16 + (n5&15) + dx ----
    int bidx[2][3];
    const int brow = 2 * w + (n5 >> 4);
    #pragma unroll
    for (int i = 0; i < 2; ++i)
        #pragma unroll
        for (int dx = 0; dx < 3; ++dx) {
            int lcol = i * 16 + (n5 & 15) + dx;
            bidx[i][dx] = (brow * 34 + lcol) * 64 + ((hl ^ (lcol & 7)) << 3);
        }

    const float* nz = noise + (size_t)b * HW;
    const int orow = ty + brow;           // output row for this lane

    int p = 0;
    for (int it = 0; it < 16; ++it) {
        const int tx = it * 32;

        // noise loads (oldest vmem of this iter)
        float nv[2];
        #pragma unroll
        for (int i = 0; i < 2; ++i)
            nv[i] = nz[orow * WW + tx + i * 16 + (n5 & 15)];

        // ---- compute from buf p: 4 ds_read_b128 -> 4 MFMA(32x32x16) per phase ----
        const ushort* bufp = &lds[A_U + p * B_U];
        f32x16 acc[2][2];
        #pragma unroll
        for (int mt = 0; mt < 2; ++mt)
            #pragma unroll
            for (int i = 0; i < 2; ++i)
                acc[mt][i] = (f32x16){0.f,0.f,0.f,0.f,0.f,0.f,0.f,0.f,
                                      0.f,0.f,0.f,0.f,0.f,0.f,0.f,0.f};

        #pragma unroll
        for (int dy = 0; dy < 3; ++dy) {
            #pragma unroll
            for (int dx = 0; dx < 3; ++dx) {
                const int off = dy * 3 + dx;
                #pragma unroll
                for (int kb = 0; kb < 4; ++kb) {
                    bf16x8 afr[2], bfr[2];
                    #pragma unroll
                    for (int mt = 0; mt < 2; ++mt)
                        afr[mt] = *(const bf16x8*)
                            &lds[(aidx[mt] + off * 64) ^ (kb << 4)];
                    #pragma unroll
                    for (int i = 0; i < 2; ++i)
                        bfr[i] = *(const bf16x8*)
                            &bufp[(bidx[i][dx] + dy * (34 * 64)) ^ (kb << 4)];
                    #pragma unroll
                    for (int mt = 0; mt < 2; ++mt)
                        #pragma unroll
                        for (int i = 0; i < 2; ++i)
                            acc[mt][i] = __builtin_amdgcn_mfma_f32_32x32x16_bf16(
                                afr[mt], bfr[i], acc[mt][i], 0, 0, 0);
                }
            }
        }

        // issue next tile's staging (younger than noise; older than stores)
        if (it < 15) {
            #pragma unroll
            for (int jj = 0; jj < 11; ++jj) {
                int j = w + jj * 4;
                if (j < 43)
                    __builtin_amdgcn_global_load_lds(
                        (const __attribute__((address_space(1))) unsigned int*)
                            (xpb + soff[jj] + (tx + 32) * 64),
                        (__attribute__((address_space(3))) unsigned int*)
                            &lds[A_U + (p ^ 1) * B_U + j * 512],
                        16, 0, 0);
            }
        }

        // ---- epilogue: +noise, +bias, lrelu*sqrt2, clamp, store (stores youngest) ----
        // C layout (m74/m101): col = lane&31 (px), row = (reg&3)+8*(reg>>2)+4*hl (co)
        #pragma unroll
        for (int mt = 0; mt < 2; ++mt) {
            #pragma unroll
            for (int i = 0; i < 2; ++i) {
                const int ocol = tx + i * 16 + (n5 & 15);
                #pragma unroll
                for (int reg = 0; reg < 16; ++reg) {
                    int co = mt * 32 + (reg & 3) + 8 * (reg >> 2) + 4 * hl;
                    float y = acc[mt][i][reg] + nv[i] + bias[co];
                    y = (y >= 0.f ? y : 0.2f * y) * 1.41421356237f;
                    y = fminf(fmaxf(y, -256.f), 256.f);
                    out[((size_t)(b * 64 + co) * HH + orow) * WW + ocol] = y;
                }
            }
        }

        // counted drain (T4): retire the 11 stage loads; leave stores in flight
        asm volatile("s_waitcnt vmcnt(63)" ::: "memory");
        __builtin_amdgcn_sched_barrier(0);
        __builtin_amdgcn_s_barrier();
        p ^= 1;
    }
}

extern "C" void kernel_launch(void* const* d_in, const int* in_sizes, int n_in,
                              void* d_out, int out_size, void* d_ws, size_t ws_size,
                              hipStream_t stream) {
    const float* x     = (const float*)d_in[0];
    const float* wsv   = (const float*)d_in[1];
    const float* noise = (const float*)d_in[2];
    const float* aw    = (const float*)d_in[3];
    const float* ab    = (const float*)d_in[4];
    const float* cw    = (const float*)d_in[5];
    const float* bias  = (const float*)d_in[6];
    float* out = (float*)d_out;

    float*  styles = (float*)d_ws;                          // 1 KB
    ushort* wb16   = (ushort*)((char*)d_ws + 1024);         // 294912 B
    ushort* xpad   = (ushort*)((char*)d_ws + (1 << 20));    // 135.3 MB

    hipFuncSetAttribute((const void*)k_conv,
                        hipFuncAttributeMaxDynamicSharedMemorySize, LDS_BYTES);

    k_styles<<<256, 64, 0, stream>>>(wsv, aw, ab, styles);
    k_wmod<<<256, 64, 0, stream>>>(cw, styles, wb16);
    k_xpose<<<8225, 256, 0, stream>>>(x, xpad);
    k_conv<<<256, 256, LDS_BYTES, stream>>>(xpad, wb16, noise, bias, out);
}

// Round 15
// 231.824 us; speedup vs baseline: 1.6453x; 1.0194x over previous
//
#include <hip/hip_runtime.h>
#include <math.h>

#define HH 512
#define WW 512
#define HW (HH * WW)
#define PW 514                    // padded width/height
#define PPIX (PW * PW)

#define A_U 36864                 // 64co*9off*64ci ushorts = 73728 B
#define B_U 22016                 // 43 loads x 512 ushorts = 44032 B per B buffer
#define LDS_BYTES ((A_U + 2 * B_U) * 2)   // 161792 B <= 160 KiB pool

typedef short bf16x8 __attribute__((ext_vector_type(8)));
typedef float f32x4  __attribute__((ext_vector_type(4)));
typedef float f32x16 __attribute__((ext_vector_type(16)));

__device__ __forceinline__ ushort f2bf(float f) {
    union { float f; uint u; } c; c.f = f;
    uint u = c.u;
    return (ushort)((u + 0x7fffu + ((u >> 16) & 1u)) >> 16);
}

__device__ __forceinline__ uint cvtpk(float a, float b) {
    uint r;
    asm("v_cvt_pk_bf16_f32 %0, %1, %2" : "=v"(r) : "v"(a), "v"(b));
    return r;
}

// ---------------- kernel 1: styles ----------------
__global__ void k_styles(const float* __restrict__ wsv, const float* __restrict__ aw,
                         const float* __restrict__ ab, float* __restrict__ styles) {
    int bid = blockIdx.x;
    int b = bid >> 6, ci = bid & 63;
    int l = threadIdx.x;
    const float* wrow = wsv + b * 512;
    const float* arow = aw + ci * 512;
    float s = 0.f;
    #pragma unroll
    for (int j = 0; j < 8; ++j)
        s += wrow[l + 64 * j] * arow[l + 64 * j];
    #pragma unroll
    for (int off = 32; off; off >>= 1)
        s += __shfl_xor(s, off, 64);
    if (l == 0)
        styles[b * 64 + ci] = s * 0.044194173824159216f + ab[ci];
}

// ------------- kernel 2: modulate+demodulate -> bf16 [b][co][off 9][ci 64] -------------
// ci-group (ci>>3) stored XORed with (co&7): conflict-free A ds_reads after a
// purely LINEAR global_load_lds stage (swizzle baked at write time). (R8/R10-proven)
__global__ void k_wmod(const float* __restrict__ cw, const float* __restrict__ styles,
                       ushort* __restrict__ wb) {
    int b = blockIdx.x >> 6, co = blockIdx.x & 63;
    int ci = threadIdx.x;
    float st = styles[b * 64 + ci];
    const float* wp = cw + (co * 64 + ci) * 9;
    float wv[9];
    float ss = 0.f;
    #pragma unroll
    for (int k = 0; k < 9; ++k) { wv[k] = wp[k] * st; ss += wv[k] * wv[k]; }
    #pragma unroll
    for (int off = 32; off; off >>= 1)
        ss += __shfl_xor(ss, off, 64);
    float dm = 1.0f / sqrtf(ss + 1e-8f);
    int cisw = ((((ci >> 3) ^ co) & 7) << 3) | (ci & 7);
    #pragma unroll
    for (int k = 0; k < 9; ++k)
        wb[((size_t)(b * 64 + co) * 9 + k) * 64 + cisw] = f2bf(wv[k] * dm);
}

// ------------- kernel 2c: x fp32 NCHW -> xp bf16 [b][gy+1][gx+1][ci], pad fused -------------
__global__ __launch_bounds__(256) void k_xpose(
    const float* __restrict__ x, ushort* __restrict__ xp) {
    const int t = threadIdx.x;
    const int bid = blockIdx.x;

    if (bid >= 8192) {            // ---- fused zeropad of the border ----
        int id = (bid - 8192) * 256 + t;
        if (id >= 4 * 2052) return;
        int b = id / 2052, r = id % 2052;
        int gyp, gxp;
        if (r < 514)       { gyp = 0;        gxp = r; }
        else if (r < 1028) { gyp = 513;      gxp = r - 514; }
        else if (r < 1540) { gyp = r - 1027; gxp = 0; }
        else               { gyp = r - 1539; gxp = 513; }
        ushort* p = xp + (((size_t)b * PW + gyp) * PW + gxp) * 64;
        uint4 z = make_uint4(0, 0, 0, 0);
        #pragma unroll
        for (int i = 0; i < 8; ++i) *(uint4*)(p + i * 8) = z;
        return;
    }

    __shared__ ushort lt[128 * 68];
    const int gxt = bid & 3;
    const int gy  = (bid >> 2) & 511;
    const int b   = bid >> 11;

    const float* xb = x + (size_t)b * 64 * HW + (size_t)gy * WW + gxt * 128;
    const int ci0 = 8 * (t >> 5);
    const int gxc = t & 31;

    f32x4 v[8];
    #pragma unroll
    for (int j = 0; j < 8; ++j)
        v[j] = *(const f32x4*)(xb + (size_t)(ci0 + j) * HW + gxc * 4);

    #pragma unroll
    for (int p = 0; p < 4; ++p) {
        int px = gxc * 4 + p;
        int rowp = ((px & 3) * 32 + (px >> 2)) * 68;
        #pragma unroll
        for (int cg = 0; cg < 2; ++cg) {
            uint lo = cvtpk(v[4 * cg + 0][p], v[4 * cg + 1][p]);
            uint hi = cvtpk(v[4 * cg + 2][p], v[4 * cg + 3][p]);
            *(uint2*)&lt[rowp + ci0 + 4 * cg] = make_uint2(lo, hi);
        }
    }
    __syncthreads();

    const int px = t >> 1, half = t & 1;
    const int rowp = ((px & 3) * 32 + (px >> 2)) * 68 + half * 32;
    uint4 o0 = *(uint4*)&lt[rowp + 0];
    uint4 o1 = *(uint4*)&lt[rowp + 8];
    uint4 o2 = *(uint4*)&lt[rowp + 16];
    uint4 o3 = *(uint4*)&lt[rowp + 24];
    ushort* dst = xp + (((size_t)b * PW + (gy + 1)) * PW + (gxt * 128 + px + 1)) * 64
                     + half * 32;
    *(uint4*)(dst + 0)  = o0;
    *(uint4*)(dst + 8)  = o1;
    *(uint4*)(dst + 16) = o2;
    *(uint4*)(dst + 24) = o3;
}

// ------------- kernel 3: persistent 4-wave MFMA conv, 32x32x16, A-in-LDS, B dbuf -------------
// 256 blocks (1/CU), 256 threads (4 waves). Block = (b, 8-row band); 16 col-tiles
// of 8 rows x 32 cols.
// R15 pipeline (T3+T4 combined): noise -> STAGE_ISSUE(next) -> compute(cur)
// -> stores(cur) -> vmcnt(63) -> raw s_barrier.
// VMEM age order: noise(2), stage(11), stores(64) = 77 outstanding; vmcnt(63)
// retires the oldest 14 = noise+stage+1 store. Stage has the WHOLE compute
// phase to land (R14 issued it post-compute -> serial stage-wait); 63 stores
// stay in flight across the barrier and drain under the next tile's compute.
__global__ __launch_bounds__(256, 1) void k_conv(
    const ushort* __restrict__ xp,    // [4][514][514][64] bf16 padded
    const ushort* __restrict__ wb,    // [4][64co][9][64ci] bf16 (swizzle baked)
    const float* __restrict__ noise,  // [4][1][512][512]
    const float* __restrict__ bias,   // [64]
    float* __restrict__ out) {        // [4][64][512][512] fp32
    extern __shared__ __align__(16) ushort lds[];

    const int t = threadIdx.x;
    const int w = t >> 6;                // wave 0..3 = row-pair
    const int lane = t & 63;
    const int n5 = lane & 31;            // MFMA N/M lane coord
    const int hl = lane >> 5;            // k-half (8 ci)
    const int blk = blockIdx.x;
    const int b = blk >> 6;
    const int band = blk & 63;
    const int ty = band * 8;

    const ushort* xpb = xp + (size_t)b * PPIX * 64;
    const ushort* wA  = wb + (size_t)b * 64 * 576;

    // ---- stage A once: 72 x 1KB linear copy ----
    #pragma unroll
    for (int jj = 0; jj < 18; ++jj) {
        int j = w + jj * 4;
        const ushort* src = wA + j * 512 + lane * 8;
        __builtin_amdgcn_global_load_lds(
            (const __attribute__((address_space(1))) unsigned int*)src,
            (__attribute__((address_space(3))) unsigned int*)&lds[j * 512],
            16, 0, 0);
    }

    // ---- B staging source offsets (tile-invariant) ----
    int soff[11];
    #pragma unroll
    for (int jj = 0; jj < 11; ++jj) {
        int j = w + jj * 4;
        if (j < 43) {
            int c = j * 64 + lane;
            int c2 = c < 2719 ? c : 2719;  // tail clamp (src only; dst stays linear)
            int cig = c2 & 7;
            int pxl = c2 >> 3;
            int row = pxl / 34;
            int lcol = pxl - row * 34;
            int gsrc = cig ^ (lcol & 7);   // pre-swizzled source ci-group (R8-proven)
            soff[jj] = ((ty + row) * PW + lcol) * 64 + gsrc * 8;
        } else soff[jj] = 0;
    }

    // ---- prologue: stage tile0 (tx=0) into buf0 ----
    #pragma unroll
    for (int jj = 0; jj < 11; ++jj) {
        int j = w + jj * 4;
        if (j < 43)
            __builtin_amdgcn_global_load_lds(
                (const __attribute__((address_space(1))) unsigned int*)(xpb + soff[jj]),
                (__attribute__((address_space(3))) unsigned int*)&lds[A_U + j * 512],
                16, 0, 0);
    }
    asm volatile("s_waitcnt vmcnt(0)" ::: "memory");
    __syncthreads();

    // ---- A read bases ----
    int aidx[2];
    #pragma unroll
    for (int mt = 0; mt < 2; ++mt)
        aidx[mt] = (mt * 32 + n5) * 576 + ((hl ^ (n5 & 7)) << 3);

    // ---- B read bases: row = 2w + (n5>>4), col = i*16 + (n5&15) + dx ----
    int bidx[2][3];
    const int brow = 2 * w + (n5 >> 4);
    #pragma unroll
    for (int i = 0; i < 2; ++i)
        #pragma unroll
        for (int dx = 0; dx < 3; ++dx) {
            int lcol = i * 16 + (n5 & 15) + dx;
            bidx[i][dx] = (brow * 34 + lcol) * 64 + ((hl ^ (lcol & 7)) << 3);
        }

    const float* nz = noise + (size_t)b * HW;
    const int orow = ty + brow;           // output row for this lane

    int p = 0;
    for (int it = 0; it < 16; ++it) {
        const int tx = it * 32;

        // noise loads (oldest vmem of this iter)
        float nv[2];
        #pragma unroll
        for (int i = 0; i < 2; ++i)
            nv[i] = nz[orow * WW + tx + i * 16 + (n5 & 15)];

        // issue next tile's staging FIRST (T3): hides under the whole compute
        if (it < 15) {
            #pragma unroll
            for (int jj = 0; jj < 11; ++jj) {
                int j = w + jj * 4;
                if (j < 43)
                    __builtin_amdgcn_global_load_lds(
                        (const __attribute__((address_space(1))) unsigned int*)
                            (xpb + soff[jj] + (tx + 32) * 64),
                        (__attribute__((address_space(3))) unsigned int*)
                            &lds[A_U + (p ^ 1) * B_U + j * 512],
                        16, 0, 0);
            }
        }

        // ---- compute from buf p: 4 ds_read_b128 -> 4 MFMA(32x32x16) per phase ----
        const ushort* bufp = &lds[A_U + p * B_U];
        f32x16 acc[2][2];
        #pragma unroll
        for (int mt = 0; mt < 2; ++mt)
            #pragma unroll
            for (int i = 0; i < 2; ++i)
                acc[mt][i] = (f32x16){0.f,0.f,0.f,0.f,0.f,0.f,0.f,0.f,
                                      0.f,0.f,0.f,0.f,0.f,0.f,0.f,0.f};

        #pragma unroll
        for (int dy = 0; dy < 3; ++dy) {
            #pragma unroll
            for (int dx = 0; dx < 3; ++dx) {
                const int off = dy * 3 + dx;
                #pragma unroll
                for (int kb = 0; kb < 4; ++kb) {
                    bf16x8 afr[2], bfr[2];
                    #pragma unroll
                    for (int mt = 0; mt < 2; ++mt)
                        afr[mt] = *(const bf16x8*)
                            &lds[(aidx[mt] + off * 64) ^ (kb << 4)];
                    #pragma unroll
                    for (int i = 0; i < 2; ++i)
                        bfr[i] = *(const bf16x8*)
                            &bufp[(bidx[i][dx] + dy * (34 * 64)) ^ (kb << 4)];
                    #pragma unroll
                    for (int mt = 0; mt < 2; ++mt)
                        #pragma unroll
                        for (int i = 0; i < 2; ++i)
                            acc[mt][i] = __builtin_amdgcn_mfma_f32_32x32x16_bf16(
                                afr[mt], bfr[i], acc[mt][i], 0, 0, 0);
                }
            }
        }

        // ---- epilogue: +noise, +bias, lrelu*sqrt2, clamp, store (stores youngest) ----
        // C layout (m74/m101): col = lane&31 (px), row = (reg&3)+8*(reg>>2)+4*hl (co)
        #pragma unroll
        for (int mt = 0; mt < 2; ++mt) {
            #pragma unroll
            for (int i = 0; i < 2; ++i) {
                const int ocol = tx + i * 16 + (n5 & 15);
                #pragma unroll
                for (int reg = 0; reg < 16; ++reg) {
                    int co = mt * 32 + (reg & 3) + 8 * (reg >> 2) + 4 * hl;
                    float y = acc[mt][i][reg] + nv[i] + bias[co];
                    y = (y >= 0.f ? y : 0.2f * y) * 1.41421356237f;
                    y = fminf(fmaxf(y, -256.f), 256.f);
                    out[((size_t)(b * 64 + co) * HH + orow) * WW + ocol] = y;
                }
            }
        }

        // counted drain (T4): retire noise+stage (oldest 14); leave stores in flight
        asm volatile("s_waitcnt vmcnt(63)" ::: "memory");
        __builtin_amdgcn_sched_barrier(0);
        __builtin_amdgcn_s_barrier();
        p ^= 1;
    }
}

extern "C" void kernel_launch(void* const* d_in, const int* in_sizes, int n_in,
                              void* d_out, int out_size, void* d_ws, size_t ws_size,
                              hipStream_t stream) {
    const float* x     = (const float*)d_in[0];
    const float* wsv   = (const float*)d_in[1];
    const float* noise = (const float*)d_in[2];
    const float* aw    = (const float*)d_in[3];
    const float* ab    = (const float*)d_in[4];
    const float* cw    = (const float*)d_in[5];
    const float* bias  = (const float*)d_in[6];
    float* out = (float*)d_out;

    float*  styles = (float*)d_ws;                          // 1 KB
    ushort* wb16   = (ushort*)((char*)d_ws + 1024);         // 294912 B
    ushort* xpad   = (ushort*)((char*)d_ws + (1 << 20));    // 135.3 MB

    hipFuncSetAttribute((const void*)k_conv,
                        hipFuncAttributeMaxDynamicSharedMemorySize, LDS_BYTES);

    k_styles<<<256, 64, 0, stream>>>(wsv, aw, ab, styles);
    k_wmod<<<256, 64, 0, stream>>>(cw, styles, wb16);
    k_xpose<<<8225, 256, 0, stream>>>(x, xpad);
    k_conv<<<256, 256, LDS_BYTES, stream>>>(xpad, wb16, noise, bias, out);
}